// Round 1
// baseline (371.886 us; speedup 1.0000x reference)
//
#include <hip/hip_runtime.h>
#include <math.h>

// Problem constants (fixed by the reference)
constexpr int ESL = 4096;
constexpr int B   = 64;
constexpr int EHS = 256;
constexpr int DHS = 256;

constexpr int NC    = 32;          // number of s-chunks
constexpr int CHUNK = ESL / NC;    // 128 s per block
constexpr int TPB   = 256;         // 4 waves
constexpr int WAVES = TPB / 64;
constexpr int SPW   = CHUNK / WAVES; // 32 s per wave (interleaved by wave id)

__device__ __forceinline__ float wave_sum(float v) {
#pragma unroll
  for (int off = 32; off > 0; off >>= 1)
    v += __shfl_xor(v, off, 64);
  return v;
}

// Pass 1: per (batch n, s-chunk c) compute online-softmax partials:
//   m = max energy, l = sum exp(e-m), acc[j] = sum exp(e-m)*h[s,n,j]
__global__ __launch_bounds__(TPB) void pass1(
    const float* __restrict__ si, const float* __restrict__ h,
    const float* __restrict__ W,  const float* __restrict__ bptr,
    float* __restrict__ ws_acc, float* __restrict__ ws_m, float* __restrict__ ws_l) {
  const int c    = blockIdx.x;
  const int n    = blockIdx.y;
  const int lane = threadIdx.x & 63;
  const int w    = threadIdx.x >> 6;

  // Weights: Wd = W[0:256], We = W[256:512]
  const float4 Wd4 = *(const float4*)(W + 4 * lane);
  const float4 We4 = *(const float4*)(W + DHS + 4 * lane);
  const float  bias = bptr[0];

  // e_dec for this batch (computed redundantly per wave) + bias folded in
  const float4 si4 = *(const float4*)(si + (size_t)n * DHS + 4 * lane);
  const float edec = wave_sum(si4.x * Wd4.x + si4.y * Wd4.y +
                              si4.z * Wd4.z + si4.w * Wd4.w) + bias;

  float  m = -1e30f, l = 0.f;
  float4 acc = make_float4(0.f, 0.f, 0.f, 0.f);

  const int    s0     = c * CHUNK + w;               // wave-interleaved s
  const float* hp     = h + ((size_t)s0 * B + n) * EHS + 4 * lane;
  const size_t stride = (size_t)WAVES * B * EHS;     // s += WAVES

  float4 h4 = *(const float4*)hp;                    // prefetch first row
#pragma unroll 4
  for (int t = 0; t < SPW; ++t) {
    float4 h4n = make_float4(0.f, 0.f, 0.f, 0.f);
    if (t + 1 < SPW) h4n = *(const float4*)(hp + (size_t)(t + 1) * stride);

    float p = h4.x * We4.x + h4.y * We4.y + h4.z * We4.z + h4.w * We4.w;
    float e = wave_sum(p) + edec;
    e = fmaxf(e, 0.f);                               // relu

    float mn  = fmaxf(m, e);
    float sc  = __expf(m - mn);                      // first iter: exp(-1e30)=0
    float wgt = __expf(e - mn);
    l = l * sc + wgt;
    acc.x = acc.x * sc + wgt * h4.x;
    acc.y = acc.y * sc + wgt * h4.y;
    acc.z = acc.z * sc + wgt * h4.z;
    acc.w = acc.w * sc + wgt * h4.w;
    m = mn;
    h4 = h4n;
  }

  // Combine the 4 waves' partials in LDS
  __shared__ float sm_m[WAVES], sm_l[WAVES];
  __shared__ float sm_acc[WAVES][EHS];
  if (lane == 0) { sm_m[w] = m; sm_l[w] = l; }
  *(float4*)&sm_acc[w][4 * lane] = acc;
  __syncthreads();

  const int j = threadIdx.x;                          // channel
  float M = fmaxf(fmaxf(sm_m[0], sm_m[1]), fmaxf(sm_m[2], sm_m[3]));
  float L = 0.f, A = 0.f;
#pragma unroll
  for (int ww = 0; ww < WAVES; ++ww) {
    float scw = __expf(sm_m[ww] - M);
    L += sm_l[ww] * scw;
    A += sm_acc[ww][j] * scw;
  }
  const size_t pidx = (size_t)n * NC + c;
  ws_acc[pidx * EHS + j] = A;
  if (j == 0) { ws_m[pidx] = M; ws_l[pidx] = L; }
}

// Pass 2: combine chunks per batch; out[n*EHS + j] = sum_c acc_c[j]*exp(m_c-M) / L
__global__ __launch_bounds__(EHS) void pass2(
    const float* __restrict__ ws_acc, const float* __restrict__ ws_m,
    const float* __restrict__ ws_l, float* __restrict__ out) {
  const int n = blockIdx.x;
  const int j = threadIdx.x;

  float M = -1e30f;
#pragma unroll
  for (int c = 0; c < NC; ++c) M = fmaxf(M, ws_m[(size_t)n * NC + c]);

  float L = 0.f, A = 0.f;
#pragma unroll
  for (int c = 0; c < NC; ++c) {
    const size_t pidx = (size_t)n * NC + c;
    float sc = __expf(ws_m[pidx] - M);
    L += ws_l[pidx] * sc;
    A += ws_acc[pidx * EHS + j] * sc;
  }
  out[(size_t)n * EHS + j] = A / L;
}

extern "C" void kernel_launch(void* const* d_in, const int* in_sizes, int n_in,
                              void* d_out, int out_size, void* d_ws, size_t ws_size,
                              hipStream_t stream) {
  const float* si   = (const float*)d_in[0]; // (1,B,DHS)
  const float* h    = (const float*)d_in[1]; // (ESL,B,EHS)
  const float* W    = (const float*)d_in[2]; // (1,EHS+DHS)
  const float* bptr = (const float*)d_in[3]; // (1,)
  float* out = (float*)d_out;                // (1,B,EHS)

  // Workspace layout: acc[B*NC*EHS] | m[B*NC] | l[B*NC]
  float* ws_acc = (float*)d_ws;
  float* ws_m   = ws_acc + (size_t)B * NC * EHS;
  float* ws_l   = ws_m + (size_t)B * NC;

  dim3 g1(NC, B);
  pass1<<<g1, TPB, 0, stream>>>(si, h, W, bptr, ws_acc, ws_m, ws_l);
  pass2<<<B, EHS, 0, stream>>>(ws_acc, ws_m, ws_l, out);
}